// Round 6
// baseline (698.860 us; speedup 1.0000x reference)
//
#include <hip/hip_runtime.h>
#include <hip/hip_bf16.h>

// ---------------- problem constants ----------------
#define BB   128
#define SS   2048
#define NPOS 262144L   // BB*SS
#define MM   50
#define DK   64
#define DV   128
#define DS   50
#define KN   5
#define NQ   1000      // distinct questions
#define NC   16        // scan chunks
#define LC   128       // SS/NC

// ---------------- workspace layout (byte offsets) ----------------
#define ATTNQ_OFF  262144L      // fp32 [1000][64] attn rows (softmaxed), cols 50..63 = 0
#define PREQ_OFF   524288L      // fp32 [1000][52] q_e-part of summary (incl. bias)
#define ALQ_OFF    786432L      // fp32 [1000] softplus alpha
#define BQ_OFF     790528L      // fp32 [1000][4] beta
#define EAQ_OFF    1048576L     // fp32 [5000][256] (erase|add rows)
#define READS_OFF  8388608L     // bf16 [NPOS][128]
#define CC_OFF     79691776L    // fp32 [NC][B][50][128]
#define DC_OFF     134217728L   // fp32 [NC][B][50][128]
#define WS_NEEDED  186646528L

// fp32 weight block offsets (floats)
#define KMo   0       // key_mem [50][64]
#define VPWo  3200    // value_proj_w TRANSPOSED [128][69]
#define VPBo  12032   // value_proj_b [128]
#define SWo   12160   // summary_w TRANSPOSED [50][192]
#define SBo   21760   // summary_b [50]
#define TWo   21810   // theta_w [50]
#define AWo   21860   // alpha_w [64]
#define BWo   21924   // beta_w TRANSPOSED [4][64]
#define SCo   22180   // [0]=theta_b [1]=alpha_b [2..5]=beta_b
#define EWTo  22192   // erase_w^T fp32 [128][128]
#define AWTo  38576   // add_w^T   fp32 [128][128]

typedef unsigned short u16;
typedef __attribute__((ext_vector_type(8))) short   short8;
typedef __attribute__((ext_vector_type(4))) float   floatx4;

static __device__ __forceinline__ float b2f(u16 u) {
    union { unsigned int i; float f; } x; x.i = ((unsigned int)u) << 16; return x.f;
}
static __device__ __forceinline__ u16 f2b(float f) {
    union { float f; unsigned int i; } x; x.f = f;
    unsigned int i = x.i;
    return (u16)((i + 0x7fffu + ((i >> 16) & 1u)) >> 16);
}
static __device__ __forceinline__ float fast_tanh(float x) {
    float xc = fminf(15.f, fmaxf(-15.f, x));
    float t = __expf(2.f * xc);
    return (t - 1.f) / (t + 1.f);
}

// ---------------- kprep: pack fp32 weights (+transposes) ----------------
__global__ __launch_bounds__(256) void kprep(
    const float* km, const float* vpw, const float* vpb,
    const float* sw, const float* sb, const float* tw, const float* tb,
    const float* aw, const float* ab, const float* bw, const float* bb,
    const float* ew_, const float* adw_, float* wf)
{
    int tid = threadIdx.x;
    for (int i = tid; i < 3200; i += 256) wf[KMo + i] = km[i];
    for (int i = tid; i < 8832; i += 256) {           // vpw_t[j][k] = vpw[k][j]
        int j = i / 69, k = i - j * 69;
        wf[VPWo + i] = vpw[k * 128 + j];
    }
    for (int i = tid; i < 128; i += 256) wf[VPBo + i] = vpb[i];
    for (int i = tid; i < 9600; i += 256) {           // sw_t[j][k] = sw[k][j]
        int j = i / 192, k = i - j * 192;
        wf[SWo + i] = sw[k * 50 + j];
    }
    for (int i = tid; i < 50; i += 256) wf[SBo + i] = sb[i];
    for (int i = tid; i < 50; i += 256) wf[TWo + i] = tw[i];
    for (int i = tid; i < 64; i += 256) wf[AWo + i] = aw[i];
    for (int i = tid; i < 256; i += 256) {            // bw_t[j][k] = bw[k][j]
        int j = i >> 6, k = i & 63;
        wf[BWo + i] = bw[k * 4 + j];
    }
    for (int i = tid; i < 16384; i += 256) {          // fp32 transposes for kear
        int j = i >> 7, k = i & 127;
        wf[EWTo + i] = ew_[k * 128 + j];
        wf[AWTo + i] = adw_[k * 128 + j];
    }
    if (tid == 0) wf[SCo + 0] = tb[0];
    if (tid == 1) wf[SCo + 1] = ab[0];
    if (tid >= 2 && tid < 6) wf[SCo + tid] = bb[tid - 2];
}

// ---------------- kq: per-question tables (lane = q) ----------------
__global__ __launch_bounds__(64) void kq(
    const float* __restrict__ qe_w, const float* __restrict__ wf,
    float* __restrict__ attnq, float* __restrict__ preq,
    float* __restrict__ alq, float* __restrict__ bq)
{
    int q = blockIdx.x * 64 + threadIdx.x;
    if (q >= NQ) return;

    float qe[64];
    const float* qrow = qe_w + (long)q * 64;
    #pragma unroll
    for (int c = 0; c < 16; ++c) {
        floatx4 vv = *(const floatx4*)(qrow + c * 4);
        qe[c*4+0] = vv[0]; qe[c*4+1] = vv[1]; qe[c*4+2] = vv[2]; qe[c*4+3] = vv[3];
    }
    float lg[50];
    const float* kmf = wf + KMo;
    #pragma unroll 2
    for (int m = 0; m < 50; ++m) {
        float acc = 0.f;
        #pragma unroll
        for (int k = 0; k < 64; ++k) acc = fmaf(qe[k], kmf[m * 64 + k], acc);
        lg[m] = acc;
    }
    float mx = -1e30f;
    #pragma unroll
    for (int m = 0; m < 50; ++m) mx = fmaxf(mx, lg[m]);
    float sum = 0.f;
    #pragma unroll
    for (int m = 0; m < 50; ++m) { lg[m] = __expf(lg[m] - mx); sum += lg[m]; }
    float inv = 1.f / sum;
    float* adst = attnq + q * 64;
    #pragma unroll
    for (int m = 0; m < 50; ++m) adst[m] = lg[m] * inv;
    #pragma unroll
    for (int m = 50; m < 64; ++m) adst[m] = 0.f;

    const float* swt = wf + SWo;
    float* pdst = preq + q * 52;
    #pragma unroll 2
    for (int j = 0; j < 50; ++j) {
        float acc = wf[SBo + j];
        #pragma unroll
        for (int k = 0; k < 64; ++k) acc = fmaf(qe[k], swt[j * 192 + 128 + k], acc);
        pdst[j] = acc;
    }
    pdst[50] = 0.f; pdst[51] = 0.f;

    float al = wf[SCo + 1];
    #pragma unroll
    for (int k = 0; k < 64; ++k) al = fmaf(qe[k], wf[AWo + k], al);
    alq[q] = (al > 20.f) ? al : log1pf(__expf(al));
    #pragma unroll
    for (int j = 0; j < 4; ++j) {
        float acc = wf[SCo + 2 + j];
        #pragma unroll
        for (int k = 0; k < 64; ++k) acc = fmaf(qe[k], wf[BWo + j * 64 + k], acc);
        bq[q * 4 + j] = acc;
    }
}

// ---------------- kear: per-(q,r) erase/add rows ----------------
__global__ __launch_bounds__(128) void kear(
    const float* __restrict__ iv_w, const float* __restrict__ wf,
    const float* __restrict__ eb, const float* __restrict__ adb,
    float* __restrict__ eaq)
{
    __shared__ float vL[128];
    int qr = blockIdx.x;
    int q = qr / 5, r = qr - q * 5;
    int j = threadIdx.x;

    const float* irow = iv_w + (long)q * 64;
    const float* vt = wf + VPWo + j * 69;
    float acc = wf[VPBo + j];
    #pragma unroll
    for (int k = 0; k < 64; ++k) acc = fmaf(irow[k], vt[k], acc);
    #pragma unroll
    for (int kk = 0; kk < KN; ++kk) {
        float rf = fmaxf(1.f - fabsf((float)kk - (float)r) * 0.25f, 0.f);
        acc = fmaf(rf, vt[64 + kk], acc);
    }
    vL[j] = acc;
    __syncthreads();

    const float* ewt = wf + EWTo + j * 128;
    const float* awt = wf + AWTo + j * 128;
    float ea = eb[j], aa = adb[j];
    #pragma unroll
    for (int k = 0; k < 128; ++k) {
        float v = vL[k];
        ea = fmaf(v, ewt[k], ea);
        aa = fmaf(v, awt[k], aa);
    }
    float* dst = eaq + (long)qr * 256;
    dst[j]       = 1.f / (1.f + __expf(-ea));
    dst[128 + j] = fast_tanh(aa);
}

// ---------------- kp1: per-chunk affine transfer function (barrier-free) ----------------
// grid = NC*B, block = 128; q/r forced wave-uniform -> attn rows via s_load
__global__ __launch_bounds__(128) void kp1(
    const int* __restrict__ questions, const int* __restrict__ responses,
    const float* __restrict__ attnq, const float* __restrict__ eaq,
    float* __restrict__ Cc, float* __restrict__ Dc)
{
    int b = blockIdx.x & (BB - 1);
    int c = blockIdx.x >> 7;
    int v = threadIdx.x;
    long tb = (long)b * SS + (long)c * LC;

    float C[50], D[50];
    #pragma unroll
    for (int m = 0; m < 50; ++m) { C[m] = 1.f; D[m] = 0.f; }

    int qt = __builtin_amdgcn_readfirstlane(questions[tb]);
    int rt = __builtin_amdgcn_readfirstlane(responses[tb]);
    const float* ea0 = eaq + (long)(qt * 5 + rt) * 256;
    float e_r = ea0[v], a_r = ea0[128 + v];
    int q_cur = qt;

    for (int t = 0; t < LC; ++t) {
        const float* ar = attnq + q_cur * 64;   // SGPR base -> s_load
        float e = e_r, a = a_r;
        if (t + 1 < LC) {
            int qn = __builtin_amdgcn_readfirstlane(questions[tb + t + 1]);
            int rn = __builtin_amdgcn_readfirstlane(responses[tb + t + 1]);
            const float* ean = eaq + (long)(qn * 5 + rn) * 256;
            e_r = ean[v]; a_r = ean[128 + v];
            q_cur = qn;
        }
        #pragma unroll
        for (int m = 0; m < 50; ++m) {
            float w  = ar[m];                   // SGPR
            float cm = fmaf(-w, e, 1.f);
            D[m] = fmaf(cm, D[m], w * a);
            C[m] *= cm;
        }
    }
    long o = ((long)(c * BB + b) * 50) * 128 + v;
    #pragma unroll
    for (int m = 0; m < 50; ++m) {
        Cc[o + (long)m * 128] = C[m];
        Dc[o + (long)m * 128] = D[m];
    }
}

// ---------------- kcomb: sequential chunk combine -> start states (into Cc) ----------------
__global__ __launch_bounds__(256) void kcomb(
    float* __restrict__ Cc, const float* __restrict__ Dc,
    const float* __restrict__ init_mem)
{
    long i = (long)blockIdx.x * 256 + threadIdx.x;   // over B*50*128
    if (i >= (long)BB * 6400) return;
    int mv = (int)(i % 6400);
    int b  = (int)(i / 6400);
    float s = init_mem[mv];
    long stride = (long)BB * 6400;
    long o = (long)b * 6400 + mv;
    for (int c = 0; c < NC; ++c) {
        float Cv = Cc[c * stride + o];
        float Dv = Dc[c * stride + o];
        Cc[c * stride + o] = s;          // overwrite C with chunk-start state
        s = fmaf(Cv, s, Dv);
    }
}

// ---------------- kp2: replay chunk from start state, emit reads ----------------
__global__ __launch_bounds__(128) void kp2(
    const int* __restrict__ questions, const int* __restrict__ responses,
    const float* __restrict__ attnq, const float* __restrict__ eaq,
    const float* __restrict__ Sc, u16* __restrict__ ws_reads)
{
    int b = blockIdx.x & (BB - 1);
    int c = blockIdx.x >> 7;
    int v = threadIdx.x;
    long tb = (long)b * SS + (long)c * LC;

    float mem[50];
    {
        long o = ((long)(c * BB + b) * 50) * 128 + v;
        #pragma unroll
        for (int m = 0; m < 50; ++m) mem[m] = Sc[o + (long)m * 128];
    }
    int qt = __builtin_amdgcn_readfirstlane(questions[tb]);
    int rt = __builtin_amdgcn_readfirstlane(responses[tb]);
    const float* ea0 = eaq + (long)(qt * 5 + rt) * 256;
    float e_r = ea0[v], a_r = ea0[128 + v];
    int q_cur = qt;

    for (int t = 0; t < LC; ++t) {
        const float* ar = attnq + q_cur * 64;   // SGPR base -> s_load
        float e = e_r, a = a_r;
        if (t + 1 < LC) {
            int qn = __builtin_amdgcn_readfirstlane(questions[tb + t + 1]);
            int rn = __builtin_amdgcn_readfirstlane(responses[tb + t + 1]);
            const float* ean = eaq + (long)(qn * 5 + rn) * 256;
            e_r = ean[v]; a_r = ean[128 + v];
            q_cur = qn;
        }
        float racc[4] = {0.f, 0.f, 0.f, 0.f};   // break fma dep chain
        #pragma unroll
        for (int m = 0; m < 50; ++m) {
            float w  = ar[m];                   // SGPR
            float mv = mem[m];
            racc[m & 3] = fmaf(w, mv, racc[m & 3]);
            mem[m] = fmaf(w, fmaf(-e, mv, a), mv);
        }
        ws_reads[(tb + t) * 128 + v] = f2b((racc[0] + racc[1]) + (racc[2] + racc[3]));
    }
}

// ---------------- k3: summary/theta + epilogue, coalesced stores (256 thr) ----------------
__global__ __launch_bounds__(256) void k3(
    const int* __restrict__ questions, const u16* __restrict__ ws_reads,
    const float* __restrict__ wf, const float* __restrict__ preq,
    const float* __restrict__ alq, const float* __restrict__ bq,
    float* __restrict__ out)
{
    __shared__ float stg[2560];          // [0,1280) logits | [1280,2560) probs
    int tid = threadIdx.x;
    long pos = (long)blockIdx.x * 256 + tid;
    int q = questions[pos];
    const float* swt = wf + SWo;
    const u16* rrow = ws_reads + pos * 128;

    float acc[52];
    const float* pq = preq + q * 52;
    #pragma unroll
    for (int i = 0; i < 13; ++i) {
        floatx4 p = *(const floatx4*)(pq + i * 4);
        acc[i*4+0] = p[0]; acc[i*4+1] = p[1]; acc[i*4+2] = p[2]; acc[i*4+3] = p[3];
    }
    float ch[64];
    #pragma unroll
    for (int cc = 0; cc < 8; ++cc) {
        short8 vv = *(const short8*)(rrow + cc * 8);
        #pragma unroll
        for (int i = 0; i < 8; ++i) ch[cc * 8 + i] = b2f((u16)vv[i]);
    }
    #pragma unroll 2
    for (int j = 0; j < 50; ++j) {
        float a = acc[j];
        #pragma unroll
        for (int k = 0; k < 64; ++k) a = fmaf(ch[k], swt[j * 192 + k], a);
        acc[j] = a;
    }
    #pragma unroll
    for (int cc = 0; cc < 8; ++cc) {
        short8 vv = *(const short8*)(rrow + 64 + cc * 8);
        #pragma unroll
        for (int i = 0; i < 8; ++i) ch[cc * 8 + i] = b2f((u16)vv[i]);
    }
    float dot = 0.f;
    #pragma unroll 2
    for (int j = 0; j < 50; ++j) {
        float a = acc[j];
        #pragma unroll
        for (int k = 0; k < 64; ++k) a = fmaf(ch[k], swt[j * 192 + 64 + k], a);
        dot = fmaf(fast_tanh(a), wf[TWo + j], dot);
    }
    float theta = fast_tanh(dot + wf[SCo + 0]);
    float alpha = alq[q];
    floatx4 bet = *(const floatx4*)(bq + q * 4);

    float inter = theta * alpha;
    float l1 = inter - bet[0];
    float l2 = l1 + inter - bet[1];
    float l3 = l2 + inter - bet[2];
    float l4 = l3 + inter - bet[3];
    float mx = fmaxf(0.f, fmaxf(fmaxf(l1, l2), fmaxf(l3, l4)));
    float e0 = __expf(0.f - mx), e1 = __expf(l1 - mx), e2 = __expf(l2 - mx);
    float e3 = __expf(l3 - mx), e4 = __expf(l4 - mx);
    float inv = 1.f / (e0 + e1 + e2 + e3 + e4);

    out[pos] = theta;                                   // coalesced
    out[NPOS + pos] = alpha;                            // coalesced
    *(floatx4*)(out + 2L * NPOS + pos * 4) = bet;       // dwordx4, contiguous

    stg[tid * 5 + 0] = 0.f;
    stg[tid * 5 + 1] = l1;  stg[tid * 5 + 2] = l2;
    stg[tid * 5 + 3] = l3;  stg[tid * 5 + 4] = l4;
    stg[1280 + tid * 5 + 0] = e0 * inv;
    stg[1280 + tid * 5 + 1] = e1 * inv;
    stg[1280 + tid * 5 + 2] = e2 * inv;
    stg[1280 + tid * 5 + 3] = e3 * inv;
    stg[1280 + tid * 5 + 4] = e4 * inv;
    __syncthreads();
    float* ol = out + 6L * NPOS + (long)blockIdx.x * 1280;
    float* op = out + 11L * NPOS + (long)blockIdx.x * 1280;
    #pragma unroll
    for (int i = 0; i < 5; ++i) {
        ol[i * 256 + tid] = stg[i * 256 + tid];         // coalesced dwords
        op[i * 256 + tid] = stg[1280 + i * 256 + tid];  // coalesced dwords
    }
}

// ---------------- host launcher ----------------
extern "C" void kernel_launch(void* const* d_in, const int* in_sizes, int n_in,
                              void* d_out, int out_size, void* d_ws, size_t ws_size,
                              hipStream_t stream)
{
    if (ws_size < (size_t)WS_NEEDED) return;   // clean fail beats OOB fault

    const int*   questions = (const int*)d_in[0];
    const int*   responses = (const int*)d_in[1];
    const float* qe_w      = (const float*)d_in[2];
    const float* iv_w      = (const float*)d_in[3];
    const float* vp_w      = (const float*)d_in[4];
    const float* vp_b      = (const float*)d_in[5];
    const float* key_mem   = (const float*)d_in[6];
    const float* init_mem  = (const float*)d_in[7];
    const float* erase_w   = (const float*)d_in[8];
    const float* erase_b   = (const float*)d_in[9];
    const float* add_w     = (const float*)d_in[10];
    const float* add_b     = (const float*)d_in[11];
    const float* summary_w = (const float*)d_in[12];
    const float* summary_b = (const float*)d_in[13];
    const float* theta_w   = (const float*)d_in[14];
    const float* theta_b   = (const float*)d_in[15];
    const float* alpha_w   = (const float*)d_in[16];
    const float* alpha_b   = (const float*)d_in[17];
    const float* beta_w    = (const float*)d_in[18];
    const float* beta_b    = (const float*)d_in[19];

    char* ws = (char*)d_ws;
    float* wf    = (float*)ws;
    float* attnq = (float*)(ws + ATTNQ_OFF);
    float* preq  = (float*)(ws + PREQ_OFF);
    float* alq   = (float*)(ws + ALQ_OFF);
    float* bq    = (float*)(ws + BQ_OFF);
    float* eaq   = (float*)(ws + EAQ_OFF);
    u16*   ws_reads = (u16*)(ws + READS_OFF);
    float* Cc    = (float*)(ws + CC_OFF);
    float* Dc    = (float*)(ws + DC_OFF);
    float* out   = (float*)d_out;

    hipLaunchKernelGGL(kprep, dim3(1), dim3(256), 0, stream,
        key_mem, vp_w, vp_b, summary_w, summary_b, theta_w, theta_b,
        alpha_w, alpha_b, beta_w, beta_b, erase_w, add_w, wf);
    hipLaunchKernelGGL(kq, dim3(16), dim3(64), 0, stream,
        qe_w, wf, attnq, preq, alq, bq);
    hipLaunchKernelGGL(kear, dim3(5000), dim3(128), 0, stream,
        iv_w, wf, erase_b, add_b, eaq);
    hipLaunchKernelGGL(kp1, dim3(NC * BB), dim3(128), 0, stream,
        questions, responses, attnq, eaq, Cc, Dc);
    hipLaunchKernelGGL(kcomb, dim3(3200), dim3(256), 0, stream,
        Cc, Dc, init_mem);
    hipLaunchKernelGGL(kp2, dim3(NC * BB), dim3(128), 0, stream,
        questions, responses, attnq, eaq, Cc, ws_reads);
    hipLaunchKernelGGL(k3, dim3(1024), dim3(256), 0, stream,
        questions, ws_reads, wf, preq, alq, bq, out);
}

// Round 7
// 611.720 us; speedup vs baseline: 1.1425x; 1.1425x over previous
//
#include <hip/hip_runtime.h>
#include <hip/hip_bf16.h>

// ---------------- problem constants ----------------
#define BB   128
#define SS   2048
#define NPOS 262144L   // BB*SS
#define MM   50
#define DK   64
#define DV   128
#define DS   50
#define KN   5
#define NQ   1000      // distinct questions
#define NC   16        // scan chunks
#define LC   128       // SS/NC

// ---------------- workspace layout (byte offsets) ----------------
#define ATTNQ_OFF  262144L      // fp32 [1000][64] attn rows (softmaxed), cols 50..63 = 0
#define PREQ_OFF   524288L      // fp32 [1000][52] q_e-part of summary (incl. bias)
#define ALQ_OFF    786432L      // fp32 [1000] softplus alpha
#define BQ_OFF     790528L      // fp32 [1000][4] beta
#define EAQ_OFF    1048576L     // fp32 [5000][256] (erase|add rows)
#define READS_OFF  8388608L     // bf16 [NPOS][128]
#define CC_OFF     75497472L    // bf16 [NC][B][50][128]
#define DC_OFF     101711872L   // bf16 [NC][B][50][128]
#define WS_NEEDED  127926272L

// fp32 weight block offsets (floats)
#define KMo   0       // key_mem [50][64]
#define VPWo  3200    // value_proj_w TRANSPOSED [128][69]
#define VPBo  12032   // value_proj_b [128]
#define SWo   12160   // summary_w TRANSPOSED [50][192]
#define SBo   21760   // summary_b [50]
#define TWo   21810   // theta_w [50]
#define AWo   21860   // alpha_w [64]
#define BWo   21924   // beta_w TRANSPOSED [4][64]
#define SCo   22180   // [0]=theta_b [1]=alpha_b [2..5]=beta_b
#define EWTo  22192   // erase_w^T fp32 [128][128]
#define AWTo  38576   // add_w^T   fp32 [128][128]

typedef unsigned short u16;
typedef __attribute__((ext_vector_type(8))) short   short8;
typedef __attribute__((ext_vector_type(4))) float   floatx4;
typedef __attribute__((ext_vector_type(2))) float   float2v;

static __device__ __forceinline__ float b2f(u16 u) {
    union { unsigned int i; float f; } x; x.i = ((unsigned int)u) << 16; return x.f;
}
static __device__ __forceinline__ u16 f2b(float f) {
    union { float f; unsigned int i; } x; x.f = f;
    unsigned int i = x.i;
    return (u16)((i + 0x7fffu + ((i >> 16) & 1u)) >> 16);
}
static __device__ __forceinline__ float fast_tanh(float x) {
    float xc = fminf(15.f, fmaxf(-15.f, x));
    float t = __expf(2.f * xc);
    return (t - 1.f) / (t + 1.f);
}
static __device__ __forceinline__ float2v splat2(float x) {
    return (float2v){x, x};
}

// ---------------- kprep: pack fp32 weights (+transposes) ----------------
__global__ __launch_bounds__(256) void kprep(
    const float* km, const float* vpw, const float* vpb,
    const float* sw, const float* sb, const float* tw, const float* tb,
    const float* aw, const float* ab, const float* bw, const float* bb,
    const float* ew_, const float* adw_, float* wf)
{
    int tid = threadIdx.x;
    for (int i = tid; i < 3200; i += 256) wf[KMo + i] = km[i];
    for (int i = tid; i < 8832; i += 256) {           // vpw_t[j][k] = vpw[k][j]
        int j = i / 69, k = i - j * 69;
        wf[VPWo + i] = vpw[k * 128 + j];
    }
    for (int i = tid; i < 128; i += 256) wf[VPBo + i] = vpb[i];
    for (int i = tid; i < 9600; i += 256) {           // sw_t[j][k] = sw[k][j]
        int j = i / 192, k = i - j * 192;
        wf[SWo + i] = sw[k * 50 + j];
    }
    for (int i = tid; i < 50; i += 256) wf[SBo + i] = sb[i];
    for (int i = tid; i < 50; i += 256) wf[TWo + i] = tw[i];
    for (int i = tid; i < 64; i += 256) wf[AWo + i] = aw[i];
    for (int i = tid; i < 256; i += 256) {            // bw_t[j][k] = bw[k][j]
        int j = i >> 6, k = i & 63;
        wf[BWo + i] = bw[k * 4 + j];
    }
    for (int i = tid; i < 16384; i += 256) {          // fp32 transposes for kear
        int j = i >> 7, k = i & 127;
        wf[EWTo + i] = ew_[k * 128 + j];
        wf[AWTo + i] = adw_[k * 128 + j];
    }
    if (tid == 0) wf[SCo + 0] = tb[0];
    if (tid == 1) wf[SCo + 1] = ab[0];
    if (tid >= 2 && tid < 6) wf[SCo + tid] = bb[tid - 2];
}

// ---------------- kq: per-question tables (lane = q) ----------------
__global__ __launch_bounds__(64) void kq(
    const float* __restrict__ qe_w, const float* __restrict__ wf,
    float* __restrict__ attnq, float* __restrict__ preq,
    float* __restrict__ alq, float* __restrict__ bq)
{
    int q = blockIdx.x * 64 + threadIdx.x;
    if (q >= NQ) return;

    float qe[64];
    const float* qrow = qe_w + (long)q * 64;
    #pragma unroll
    for (int c = 0; c < 16; ++c) {
        floatx4 vv = *(const floatx4*)(qrow + c * 4);
        qe[c*4+0] = vv[0]; qe[c*4+1] = vv[1]; qe[c*4+2] = vv[2]; qe[c*4+3] = vv[3];
    }
    float lg[50];
    const float* kmf = wf + KMo;
    #pragma unroll 2
    for (int m = 0; m < 50; ++m) {
        float acc = 0.f;
        #pragma unroll
        for (int k = 0; k < 64; ++k) acc = fmaf(qe[k], kmf[m * 64 + k], acc);
        lg[m] = acc;
    }
    float mx = -1e30f;
    #pragma unroll
    for (int m = 0; m < 50; ++m) mx = fmaxf(mx, lg[m]);
    float sum = 0.f;
    #pragma unroll
    for (int m = 0; m < 50; ++m) { lg[m] = __expf(lg[m] - mx); sum += lg[m]; }
    float inv = 1.f / sum;
    float* adst = attnq + q * 64;
    #pragma unroll
    for (int m = 0; m < 50; ++m) adst[m] = lg[m] * inv;
    #pragma unroll
    for (int m = 50; m < 64; ++m) adst[m] = 0.f;

    const float* swt = wf + SWo;
    float* pdst = preq + q * 52;
    #pragma unroll 2
    for (int j = 0; j < 50; ++j) {
        float acc = wf[SBo + j];
        #pragma unroll
        for (int k = 0; k < 64; ++k) acc = fmaf(qe[k], swt[j * 192 + 128 + k], acc);
        pdst[j] = acc;
    }
    pdst[50] = 0.f; pdst[51] = 0.f;

    float al = wf[SCo + 1];
    #pragma unroll
    for (int k = 0; k < 64; ++k) al = fmaf(qe[k], wf[AWo + k], al);
    alq[q] = (al > 20.f) ? al : log1pf(__expf(al));
    #pragma unroll
    for (int j = 0; j < 4; ++j) {
        float acc = wf[SCo + 2 + j];
        #pragma unroll
        for (int k = 0; k < 64; ++k) acc = fmaf(qe[k], wf[BWo + j * 64 + k], acc);
        bq[q * 4 + j] = acc;
    }
}

// ---------------- kear: per-(q,r) erase/add rows ----------------
__global__ __launch_bounds__(128) void kear(
    const float* __restrict__ iv_w, const float* __restrict__ wf,
    const float* __restrict__ eb, const float* __restrict__ adb,
    float* __restrict__ eaq)
{
    __shared__ float vL[128];
    int qr = blockIdx.x;
    int q = qr / 5, r = qr - q * 5;
    int j = threadIdx.x;

    const float* irow = iv_w + (long)q * 64;
    const float* vt = wf + VPWo + j * 69;
    float acc = wf[VPBo + j];
    #pragma unroll
    for (int k = 0; k < 64; ++k) acc = fmaf(irow[k], vt[k], acc);
    #pragma unroll
    for (int kk = 0; kk < KN; ++kk) {
        float rf = fmaxf(1.f - fabsf((float)kk - (float)r) * 0.25f, 0.f);
        acc = fmaf(rf, vt[64 + kk], acc);
    }
    vL[j] = acc;
    __syncthreads();

    const float* ewt = wf + EWTo + j * 128;
    const float* awt = wf + AWTo + j * 128;
    float ea = eb[j], aa = adb[j];
    #pragma unroll
    for (int k = 0; k < 128; ++k) {
        float v = vL[k];
        ea = fmaf(v, ewt[k], ea);
        aa = fmaf(v, awt[k], aa);
    }
    float* dst = eaq + (long)qr * 256;
    dst[j]       = 1.f / (1.f + __expf(-ea));
    dst[128 + j] = fast_tanh(aa);
}

// ---------------- kp1: per-chunk affine transfer function (packed fp32) ----------------
// grid = NC*B, block = 128; q/r wave-uniform -> attn rows via s_load, m in float2 pairs
__global__ __launch_bounds__(128) void kp1(
    const int* __restrict__ questions, const int* __restrict__ responses,
    const float* __restrict__ attnq, const float* __restrict__ eaq,
    u16* __restrict__ Cc, u16* __restrict__ Dc)
{
    int b = blockIdx.x & (BB - 1);
    int c = blockIdx.x >> 7;
    int v = threadIdx.x;
    long tb = (long)b * SS + (long)c * LC;

    float2v C[25], D[25];
    #pragma unroll
    for (int i = 0; i < 25; ++i) { C[i] = splat2(1.f); D[i] = splat2(0.f); }

    int qt = __builtin_amdgcn_readfirstlane(questions[tb]);
    int rt = __builtin_amdgcn_readfirstlane(responses[tb]);
    const float* ea0 = eaq + (long)(qt * 5 + rt) * 256;
    float e_r = ea0[v], a_r = ea0[128 + v];
    int q_cur = qt;

    for (int t = 0; t < LC; ++t) {
        const float2v* ar = (const float2v*)(attnq + q_cur * 64);   // uniform -> s_load pairs
        float2v e2 = splat2(e_r), a2 = splat2(a_r);
        if (t + 1 < LC) {
            int qn = __builtin_amdgcn_readfirstlane(questions[tb + t + 1]);
            int rn = __builtin_amdgcn_readfirstlane(responses[tb + t + 1]);
            const float* ean = eaq + (long)(qn * 5 + rn) * 256;
            e_r = ean[v]; a_r = ean[128 + v];
            q_cur = qn;
        }
        #pragma unroll
        for (int i = 0; i < 25; ++i) {
            float2v w  = ar[i];                    // SGPR pair
            float2v cm = splat2(1.f) - w * e2;     // v_pk_fma
            D[i] = cm * D[i] + w * a2;             // v_pk_mul + v_pk_fma
            C[i] = C[i] * cm;                      // v_pk_mul
        }
    }
    long o = ((long)(c * BB + b) * 50) * 128 + v;
    #pragma unroll
    for (int i = 0; i < 25; ++i) {
        Cc[o + (long)(2*i)   * 128] = f2b(C[i].x);
        Cc[o + (long)(2*i+1) * 128] = f2b(C[i].y);
        Dc[o + (long)(2*i)   * 128] = f2b(D[i].x);
        Dc[o + (long)(2*i+1) * 128] = f2b(D[i].y);
    }
}

// ---------------- kcomb: sequential chunk combine -> start states (into Cc) ----------------
__global__ __launch_bounds__(256) void kcomb(
    u16* __restrict__ Cc, const u16* __restrict__ Dc,
    const float* __restrict__ init_mem)
{
    long i = (long)blockIdx.x * 256 + threadIdx.x;   // over B*50*128
    if (i >= (long)BB * 6400) return;
    int mv = (int)(i % 6400);
    int b  = (int)(i / 6400);
    float s = init_mem[mv];
    long stride = (long)BB * 6400;
    long o = (long)b * 6400 + mv;
    for (int c = 0; c < NC; ++c) {
        float Cv = b2f(Cc[c * stride + o]);
        float Dv = b2f(Dc[c * stride + o]);
        Cc[c * stride + o] = f2b(s);     // overwrite C with chunk-start state
        s = fmaf(Cv, s, Dv);
    }
}

// ---------------- kp2: replay chunk from start state, emit reads (packed fp32) ----------------
__global__ __launch_bounds__(128) void kp2(
    const int* __restrict__ questions, const int* __restrict__ responses,
    const float* __restrict__ attnq, const float* __restrict__ eaq,
    const u16* __restrict__ Sc, u16* __restrict__ ws_reads)
{
    int b = blockIdx.x & (BB - 1);
    int c = blockIdx.x >> 7;
    int v = threadIdx.x;
    long tb = (long)b * SS + (long)c * LC;

    float2v M[25];
    {
        long o = ((long)(c * BB + b) * 50) * 128 + v;
        #pragma unroll
        for (int i = 0; i < 25; ++i)
            M[i] = (float2v){ b2f(Sc[o + (long)(2*i) * 128]),
                              b2f(Sc[o + (long)(2*i+1) * 128]) };
    }
    int qt = __builtin_amdgcn_readfirstlane(questions[tb]);
    int rt = __builtin_amdgcn_readfirstlane(responses[tb]);
    const float* ea0 = eaq + (long)(qt * 5 + rt) * 256;
    float e_r = ea0[v], a_r = ea0[128 + v];
    int q_cur = qt;

    for (int t = 0; t < LC; ++t) {
        const float2v* ar = (const float2v*)(attnq + q_cur * 64);   // uniform -> s_load pairs
        float2v e2 = splat2(e_r), a2 = splat2(a_r);
        if (t + 1 < LC) {
            int qn = __builtin_amdgcn_readfirstlane(questions[tb + t + 1]);
            int rn = __builtin_amdgcn_readfirstlane(responses[tb + t + 1]);
            const float* ean = eaq + (long)(qn * 5 + rn) * 256;
            e_r = ean[v]; a_r = ean[128 + v];
            q_cur = qn;
        }
        float2v r0 = splat2(0.f), r1 = splat2(0.f);    // break fma dep chain
        #pragma unroll
        for (int i = 0; i < 25; ++i) {
            float2v w = ar[i];
            float2v m = M[i];
            if (i & 1) r1 = r1 + w * m;                 // v_pk_fma
            else       r0 = r0 + w * m;
            M[i] = m + w * (a2 - e2 * m);               // 2x v_pk_fma
        }
        float2v rs = r0 + r1;
        ws_reads[(tb + t) * 128 + v] = f2b(rs.x + rs.y);
    }
}

// ---------------- k3: summary/theta + epilogue, packed k-loops, coalesced stores ----------------
__global__ __launch_bounds__(256) void k3(
    const int* __restrict__ questions, const u16* __restrict__ ws_reads,
    const float* __restrict__ wf, const float* __restrict__ preq,
    const float* __restrict__ alq, const float* __restrict__ bq,
    float* __restrict__ out)
{
    __shared__ float stg[2560];          // [0,1280) logits | [1280,2560) probs
    int tid = threadIdx.x;
    long pos = (long)blockIdx.x * 256 + tid;
    int q = questions[pos];
    const float* swt = wf + SWo;
    const u16* rrow = ws_reads + pos * 128;

    float acc[52];
    const float* pq = preq + q * 52;
    #pragma unroll
    for (int i = 0; i < 13; ++i) {
        floatx4 p = *(const floatx4*)(pq + i * 4);
        acc[i*4+0] = p[0]; acc[i*4+1] = p[1]; acc[i*4+2] = p[2]; acc[i*4+3] = p[3];
    }
    float2v ch2[32];
    #pragma unroll
    for (int cc = 0; cc < 8; ++cc) {
        short8 vv = *(const short8*)(rrow + cc * 8);
        #pragma unroll
        for (int i = 0; i < 4; ++i)
            ch2[cc*4+i] = (float2v){ b2f((u16)vv[2*i]), b2f((u16)vv[2*i+1]) };
    }
    #pragma unroll 2
    for (int j = 0; j < 50; ++j) {
        const float2v* sw2 = (const float2v*)(swt + j * 192);   // uniform
        float2v a2 = splat2(0.f);
        #pragma unroll
        for (int k = 0; k < 32; ++k) a2 = a2 + ch2[k] * sw2[k]; // v_pk_fma
        acc[j] += a2.x + a2.y;
    }
    #pragma unroll
    for (int cc = 0; cc < 8; ++cc) {
        short8 vv = *(const short8*)(rrow + 64 + cc * 8);
        #pragma unroll
        for (int i = 0; i < 4; ++i)
            ch2[cc*4+i] = (float2v){ b2f((u16)vv[2*i]), b2f((u16)vv[2*i+1]) };
    }
    float dot = 0.f;
    #pragma unroll 2
    for (int j = 0; j < 50; ++j) {
        const float2v* sw2 = (const float2v*)(swt + j * 192 + 64);
        float2v a2 = splat2(0.f);
        #pragma unroll
        for (int k = 0; k < 32; ++k) a2 = a2 + ch2[k] * sw2[k];
        float a = acc[j] + a2.x + a2.y;
        dot = fmaf(fast_tanh(a), wf[TWo + j], dot);
    }
    float theta = fast_tanh(dot + wf[SCo + 0]);
    float alpha = alq[q];
    floatx4 bet = *(const floatx4*)(bq + q * 4);

    float inter = theta * alpha;
    float l1 = inter - bet[0];
    float l2 = l1 + inter - bet[1];
    float l3 = l2 + inter - bet[2];
    float l4 = l3 + inter - bet[3];
    float mx = fmaxf(0.f, fmaxf(fmaxf(l1, l2), fmaxf(l3, l4)));
    float e0 = __expf(0.f - mx), e1 = __expf(l1 - mx), e2 = __expf(l2 - mx);
    float e3 = __expf(l3 - mx), e4 = __expf(l4 - mx);
    float inv = 1.f / (e0 + e1 + e2 + e3 + e4);

    out[pos] = theta;                                   // coalesced
    out[NPOS + pos] = alpha;                            // coalesced
    *(floatx4*)(out + 2L * NPOS + pos * 4) = bet;       // dwordx4, contiguous

    stg[tid * 5 + 0] = 0.f;
    stg[tid * 5 + 1] = l1;  stg[tid * 5 + 2] = l2;
    stg[tid * 5 + 3] = l3;  stg[tid * 5 + 4] = l4;
    stg[1280 + tid * 5 + 0] = e0 * inv;
    stg[1280 + tid * 5 + 1] = e1 * inv;
    stg[1280 + tid * 5 + 2] = e2 * inv;
    stg[1280 + tid * 5 + 3] = e3 * inv;
    stg[1280 + tid * 5 + 4] = e4 * inv;
    __syncthreads();
    float* ol = out + 6L * NPOS + (long)blockIdx.x * 1280;
    float* op = out + 11L * NPOS + (long)blockIdx.x * 1280;
    #pragma unroll
    for (int i = 0; i < 5; ++i) {
        ol[i * 256 + tid] = stg[i * 256 + tid];         // coalesced dwords
        op[i * 256 + tid] = stg[1280 + i * 256 + tid];  // coalesced dwords
    }
}

// ---------------- host launcher ----------------
extern "C" void kernel_launch(void* const* d_in, const int* in_sizes, int n_in,
                              void* d_out, int out_size, void* d_ws, size_t ws_size,
                              hipStream_t stream)
{
    if (ws_size < (size_t)WS_NEEDED) return;   // clean fail beats OOB fault

    const int*   questions = (const int*)d_in[0];
    const int*   responses = (const int*)d_in[1];
    const float* qe_w      = (const float*)d_in[2];
    const float* iv_w      = (const float*)d_in[3];
    const float* vp_w      = (const float*)d_in[4];
    const float* vp_b      = (const float*)d_in[5];
    const float* key_mem   = (const float*)d_in[6];
    const float* init_mem  = (const float*)d_in[7];
    const float* erase_w   = (const float*)d_in[8];
    const float* erase_b   = (const float*)d_in[9];
    const float* add_w     = (const float*)d_in[10];
    const float* add_b     = (const float*)d_in[11];
    const float* summary_w = (const float*)d_in[12];
    const float* summary_b = (const float*)d_in[13];
    const float* theta_w   = (const float*)d_in[14];
    const float* theta_b   = (const float*)d_in[15];
    const float* alpha_w   = (const float*)d_in[16];
    const float* alpha_b   = (const float*)d_in[17];
    const float* beta_w    = (const float*)d_in[18];
    const float* beta_b    = (const float*)d_in[19];

    char* ws = (char*)d_ws;
    float* wf    = (float*)ws;
    float* attnq = (float*)(ws + ATTNQ_OFF);
    float* preq  = (float*)(ws + PREQ_OFF);
    float* alq   = (float*)(ws + ALQ_OFF);
    float* bq    = (float*)(ws + BQ_OFF);
    float* eaq   = (float*)(ws + EAQ_OFF);
    u16*   ws_reads = (u16*)(ws + READS_OFF);
    u16*   Cc    = (u16*)(ws + CC_OFF);
    u16*   Dc    = (u16*)(ws + DC_OFF);
    float* out   = (float*)d_out;

    hipLaunchKernelGGL(kprep, dim3(1), dim3(256), 0, stream,
        key_mem, vp_w, vp_b, summary_w, summary_b, theta_w, theta_b,
        alpha_w, alpha_b, beta_w, beta_b, erase_w, add_w, wf);
    hipLaunchKernelGGL(kq, dim3(16), dim3(64), 0, stream,
        qe_w, wf, attnq, preq, alq, bq);
    hipLaunchKernelGGL(kear, dim3(5000), dim3(128), 0, stream,
        iv_w, wf, erase_b, add_b, eaq);
    hipLaunchKernelGGL(kp1, dim3(NC * BB), dim3(128), 0, stream,
        questions, responses, attnq, eaq, Cc, Dc);
    hipLaunchKernelGGL(kcomb, dim3(3200), dim3(256), 0, stream,
        Cc, Dc, init_mem);
    hipLaunchKernelGGL(kp2, dim3(NC * BB), dim3(128), 0, stream,
        questions, responses, attnq, eaq, Cc, ws_reads);
    hipLaunchKernelGGL(k3, dim3(1024), dim3(256), 0, stream,
        questions, ws_reads, wf, preq, alq, bq, out);
}